// Round 4
// baseline (496.368 us; speedup 1.0000x reference)
//
#include <hip/hip_runtime.h>

// RWKV WKV forward — R8: 2 independent blocks/CU (32-channel groups).
//
// Identity: with P=(num,den) scaled by 2^m, the step is the linear recurrence
// P' = 2^{tds} P + 2^{kts} (v,1), decay channel-constant => associative.
//
// R8 rationale: R5-R7 all land at ~125 us, VALUBusy ~34%, hbm ~34% of
// achievable — the two 34%s sum to the period: with ONE 16-wave workgroup
// per CU, barrier phases and memory phases serialize (all resident waves
// stall together). Fix: 512 blocks of 1024 thr = 2 co-resident workgroups
// per CU (2048 thr = HW max), each an independent barrier domain; one
// block's stalls are filled by the other's compute.
//
// Geometry: block owns 32 contiguous channels. Lane l: channel c=l&31,
// half s=l>>5. Tile = 256 steps; wave w covers steps [w*16,(w+1)*16);
// half s scans its 8 steps locally. Halves exchange totals via
// __shfl_xor(,32); combined 16-step wave summary -> smry; ONE barrier;
// block compose over smry[0..w-1] (dseg16); half 1 additionally composes
// half 0's totals (dseg8); phase B = serial replay with output stores.
// Wave 15 / half 0 computes the tile carry from its block-incoming state
// + combined wave summary (off the phase-B path).
// k/v double-buffered in registers (issue-early prefetch, 2x-unrolled tile
// loop => compile-time buffer alternation); BARR is lgkmcnt-only so vmem
// prefetch stays in flight across it. VGPR must stay <=64 so both blocks
// fit (8 waves/SIMD): serial phase B (no prefix arrays), launch_bounds
// (1024, 8).

#define TILE   256
#define NW     16
#define WSTEPS 16          // steps per wave
#define SUBL   8           // steps per lane (half-wave)

#define BARR  asm volatile("s_waitcnt lgkmcnt(0)\n\ts_barrier" ::: "memory")

__device__ __forceinline__ float ex2(float x)  { return __builtin_amdgcn_exp2f(x); }
__device__ __forceinline__ float rcpf(float x) { return __builtin_amdgcn_rcpf(x); }

// Merge summary (sm,sn,sd) of length len (decay dlen = len*tds) into state.
__device__ __forceinline__ void merge(float& M, float& N, float& D,
                                      float dlen, float sm, float sn, float sd)
{
    const float Md = M + dlen;
    const float d  = Md - sm;
    const float e  = ex2(-fabsf(d));
    const bool  c  = d >= 0.f;
    const float a  = c ? 1.f : e;
    const float bb = c ? e : 1.f;
    N = a * N + bb * sn;
    D = a * D + bb * sd;
    M = fmaxf(Md, sm);
}

__global__ __launch_bounds__(1024, 8)
void wkv_fwd(const float* __restrict__ td_in, const float* __restrict__ kin,
             const float* __restrict__ tf_in, const float* __restrict__ vin,
             const float* __restrict__ m0, const float* __restrict__ n0,
             const float* __restrict__ d0,
             float* __restrict__ out, float* __restrict__ m_out,
             float* __restrict__ n_out, float* __restrict__ dn_out,
             int B, int S, int H)
{
    __shared__ float smry[2][NW][3][32];     // 12 KiB (double-buffered)
    __shared__ float cry[2][3][32];          // 768 B

    const int tid  = threadIdx.x;
    const int lane = tid & 63;
    const int w    = tid >> 6;               // wave id 0..15
    const int c    = lane & 31;              // channel within group
    const int s    = lane >> 5;              // half: 0 = first 8 steps

    const int bpb = H >> 5;                  // 32-ch groups per batch
    const int b   = blockIdx.x / bpb;
    const int hb  = (blockIdx.x - b * bpb) << 5;
    const int h   = hb + c;
    const int g   = b * H + h;

    constexpr float Cc = 1.4426950408889634f;   // log2(e)
    constexpr float IC = 0.6931471805599453f;   // ln(2)

    const float tds    = -ex2(td_in[h] * Cc) * Cc;  // per-step decay (log2)
    const float tfs    = tf_in[h] * Cc;
    const float dseg8  = tds * (float)SUBL;
    const float dseg16 = tds * (float)WSTEPS;

    if (w == 0 && s == 0) {                   // tile-0 carry = init state
        cry[0][0][c] = m0[g] * Cc;
        cry[0][1][c] = n0[g];
        cry[0][2][c] = d0[g];
    }

    const size_t base = (size_t)b * (size_t)S * (size_t)H + (size_t)hb;
    const float* gk = kin + base;
    const float* gv = vin + base;
    float*       go = out + base;

    const int row0   = w * WSTEPS + s * SUBL; // this lane's first row in tile
    const int ntiles = S / TILE;

    float fM = 0.f, fN = 0.f, fD = 0.f;       // (w15,s0) final state

    // Register double-buffers for this lane's 8 (k,v) rows.
    float ka[SUBL], va[SUBL], kb[SUBL], vb[SUBL];

    // Prologue: issue loads for tile 0 into set A.
    #pragma unroll
    for (int j = 0; j < SUBL; ++j) {
        ka[j] = gk[(size_t)(row0 + j) * (size_t)H + c];
        va[j] = gv[(size_t)(row0 + j) * (size_t)H + c];
    }

    auto body = [&](int it, float (&ck)[SUBL], float (&cv)[SUBL],
                    float (&nk)[SUBL], float (&nv)[SUBL])
                __attribute__((always_inline)) -> void {
        // Issue-early prefetch of tile it+1 (no wait precedes this; the
        // compiler's auto-vmcnt before first ck use waits only on the
        // older current-tile loads).
        if (it + 1 < ntiles) {
            const size_t r1 = (size_t)(it + 1) * TILE + row0;
            #pragma unroll
            for (int j = 0; j < SUBL; ++j) {
                nk[j] = gk[(r1 + j) * (size_t)H + c];
                nv[j] = gv[(r1 + j) * (size_t)H + c];
            }
        }

        const int p = it & 1;

        // ---- Phase A: 8-step local scan (neutral init); scale k in place --
        float lm = -1e30f, ln = 0.f, ld = 0.f;
        #pragma unroll
        for (int j = 0; j < SUBL; ++j) {
            const float kt = ck[j] * Cc;
            ck[j] = kt;                        // keep scaled for phase B
            const float vt  = cv[j];
            const float mpd = lm + tds;
            const float d   = mpd - kt;        // max-trick: one factor is 1
            const float e   = ex2(-fabsf(d));
            const bool  cc  = d >= 0.f;
            const float e1  = cc ? 1.f : e;
            const float e2  = cc ? e : 1.f;
            ln = e1 * ln + e2 * vt;
            ld = e1 * ld + e2;
            lm = fmaxf(mpd, kt);
        }

        // ---- Exchange halves: each half gets the other's totals ----------
        const float om = __shfl_xor(lm, 32);
        const float on = __shfl_xor(ln, 32);
        const float od = __shfl_xor(ld, 32);

        // Combined 16-step wave summary (identical in both halves).
        float wm = s ? om : lm, wn = s ? on : ln, wd = s ? od : ld;
        {
            const float sm2 = s ? lm : om;
            const float sn2 = s ? ln : on;
            const float sd2 = s ? ld : od;
            merge(wm, wn, wd, dseg8, sm2, sn2, sd2);
        }
        if (s == 0) {
            smry[p][w][0][c] = wm;
            smry[p][w][1][c] = wn;
            smry[p][w][2][c] = wd;
        }
        BARR;                                 // only barrier per tile
                                              // (lgkmcnt only — vmem
                                              //  prefetch stays in flight)

        // ---- Block compose: incoming state at step w*16 ------------------
        float M = cry[p][0][c];
        float N = cry[p][1][c];
        float D = cry[p][2][c];
        #pragma unroll
        for (int j = 0; j < NW - 1; ++j) {
            const float sm = smry[p][j][0][c];
            const float sn = smry[p][j][1][c];
            const float sd = smry[p][j][2][c];
            if (j < w) merge(M, N, D, dseg16, sm, sn, sd);
        }

        // Wave 15 / half 0: tile carry (incoming + combined wave summary).
        if (w == NW - 1 && s == 0) {
            fM = M; fN = N; fD = D;
            merge(fM, fN, fD, dseg16, wm, wn, wd);
            cry[p ^ 1][0][c] = fM;
            cry[p ^ 1][1][c] = fN;
            cry[p ^ 1][2][c] = fD;
        }

        // Half 1: advance through half 0's 8 steps (om/on/od = its totals).
        if (s == 1) merge(M, N, D, dseg8, om, on, od);

        // ---- Phase B: serial replay with output stores -------------------
        float* po = go + ((size_t)it * TILE + row0) * (size_t)H;
        #pragma unroll
        for (int j = 0; j < SUBL; ++j) {
            const float kt  = ck[j];
            const float vt  = cv[j];
            const float ktf = kt + tfs;
            const float dd  = M - ktf;
            const float eo  = ex2(-fabsf(dd));
            const bool  co  = dd >= 0.f;
            const float e1o = co ? 1.f : eo;
            const float e2o = co ? eo : 1.f;
            po[(size_t)j * H + c] =
                (e1o * N + e2o * vt) * rcpf(fmaf(e1o, D, e2o));
            const float mpd = M + tds;
            const float ds_ = mpd - kt;
            const float es  = ex2(-fabsf(ds_));
            const bool  cs  = ds_ >= 0.f;
            const float e1s = cs ? 1.f : es;
            const float e2s = cs ? es : 1.f;
            N = e1s * N + e2s * vt;
            D = e1s * D + e2s;
            M = fmaxf(mpd, kt);
        }
    };

    int it = 0;
    for (; it + 1 < ntiles; it += 2) {
        body(it,     ka, va, kb, vb);
        body(it + 1, kb, vb, ka, va);
    }
    if (it < ntiles) body(it, ka, va, kb, vb);

    if (w == NW - 1 && s == 0) {              // final states
        m_out[g]  = fM * IC;
        n_out[g]  = fN;
        dn_out[g] = fD;
    }
}

// Safety fallback (serial per channel) for shapes the tiled kernel can't take.
__global__ __launch_bounds__(64)
void wkv_fwd_serial(const float* __restrict__ td_in, const float* __restrict__ kin,
                    const float* __restrict__ tf_in, const float* __restrict__ vin,
                    const float* __restrict__ m0, const float* __restrict__ n0,
                    const float* __restrict__ d0,
                    float* __restrict__ out, float* __restrict__ m_out,
                    float* __restrict__ n_out, float* __restrict__ dn_out,
                    int B, int S, int H)
{
    const int g = blockIdx.x * 64 + threadIdx.x;
    if (g >= B * H) return;
    const int b = g / H;
    const int h = g - b * H;
    constexpr float Cc = 1.4426950408889634f, IC = 0.6931471805599453f;
    const float tds = -ex2(td_in[h] * Cc) * Cc;
    const float tfs = tf_in[h] * Cc;
    float M = m0[g] * Cc, N = n0[g], D = d0[g];
    const size_t base = (size_t)b * S * H + h;
    for (int t = 0; t < S; ++t) {
        const float kt  = kin[base + (size_t)t * H] * Cc;
        const float vt  = vin[base + (size_t)t * H];
        const float ktf = kt + tfs;
        const float mo  = fmaxf(M, ktf);
        const float e1o = ex2(M - mo), e2o = ex2(ktf - mo);
        out[base + (size_t)t * H] = (e1o * N + e2o * vt) * rcpf(e1o * D + e2o);
        const float mpd = M + tds;
        const float ms  = fmaxf(mpd, kt);
        const float e1s = ex2(mpd - ms), e2s = ex2(kt - ms);
        N = e1s * N + e2s * vt;
        D = e1s * D + e2s;
        M = ms;
    }
    m_out[g] = M * IC; n_out[g] = N; dn_out[g] = D;
}

extern "C" void kernel_launch(void* const* d_in, const int* in_sizes, int n_in,
                              void* d_out, int out_size, void* d_ws, size_t ws_size,
                              hipStream_t stream)
{
    const float* time_decay = (const float*)d_in[0];
    const float* key        = (const float*)d_in[1];
    const float* time_first = (const float*)d_in[2];
    const float* value      = (const float*)d_in[3];
    const float* max_state  = (const float*)d_in[4];
    const float* num_state  = (const float*)d_in[5];
    const float* den_state  = (const float*)d_in[6];

    const int H  = in_sizes[0];
    const int BH = in_sizes[4];
    const int B  = BH / H;
    const int S  = in_sizes[1] / BH;

    float* out    = (float*)d_out;
    float* m_out  = out + (size_t)B * (size_t)S * (size_t)H;
    float* n_out  = m_out + BH;
    float* dn_out = n_out + BH;

    if ((H % 32 == 0) && (S % TILE == 0)) {
        const int grid = BH / 32;               // 512 blocks = 2 per CU
        wkv_fwd<<<grid, 1024, 0, stream>>>(time_decay, key, time_first, value,
                                           max_state, num_state, den_state,
                                           out, m_out, n_out, dn_out, B, S, H);
    } else {
        const int grid = (BH + 63) / 64;
        wkv_fwd_serial<<<grid, 64, 0, stream>>>(time_decay, key, time_first, value,
                                                max_state, num_state, den_state,
                                                out, m_out, n_out, dn_out, B, S, H);
    }
}

// Round 5
// 350.479 us; speedup vs baseline: 1.4163x; 1.4163x over previous
//
#include <hip/hip_runtime.h>

// RWKV WKV forward — R9: 2 independent 512-thr blocks/CU, no spills.
//
// Identity: with P=(num,den) scaled by 2^m, the step is the linear recurrence
// P' = 2^{tds} P + 2^{kts} (v,1), decay channel-constant => associative.
//
// R8 post-mortem: launch_bounds(1024,8) capped VGPR at 64 -> the register
// double-buffers spilled to scratch (VGPR_Count=32, hbm_bytes 269->889 MB,
// dur 124->288us). The 2-domain hypothesis was never tested.
// R9: 512-thr blocks (8 waves) owning 32 channels; grid = BH/32 = 512 =
// 2 blocks/CU; launch_bounds(512,4) -> 128 VGPR cap (usage ~70, no spill).
// Same per-CU thread count as R7 (1024) but TWO independent barrier
// domains: one block's barrier/memory stall is filled by the other's
// compute.
//
// Geometry: lane l: channel c=l&31, half s=l>>5. Tile = 128 steps; wave w
// covers steps [w*16,(w+1)*16); half s scans its 8 steps locally. Halves
// exchange totals via __shfl_xor(,32); combined 16-step wave summary ->
// smry; ONE (lgkmcnt-only) barrier; block compose over smry[0..w-1]
// (dseg16); half 1 additionally composes half 0's totals (dseg8); phase B
// serial replay with coalesced 128 B half-wave stores. Wave 7 / half 0
// computes the tile carry (off the phase-B path). k/v double-buffered in
// registers, issue-early prefetch (2x-unrolled tile loop => compile-time
// buffer alternation); vmem prefetch stays in flight across the barrier.

#define TILE   128
#define NW     8
#define WSTEPS 16          // steps per wave
#define SUBL   8           // steps per lane (half-wave)

#define BARR  asm volatile("s_waitcnt lgkmcnt(0)\n\ts_barrier" ::: "memory")

__device__ __forceinline__ float ex2(float x)  { return __builtin_amdgcn_exp2f(x); }
__device__ __forceinline__ float rcpf(float x) { return __builtin_amdgcn_rcpf(x); }

// Merge summary (sm,sn,sd) spanning decay dlen into state (M,N,D).
__device__ __forceinline__ void merge(float& M, float& N, float& D,
                                      float dlen, float sm, float sn, float sd)
{
    const float Md = M + dlen;
    const float d  = Md - sm;
    const float e  = ex2(-fabsf(d));
    const bool  c  = d >= 0.f;
    const float a  = c ? 1.f : e;
    const float bb = c ? e : 1.f;
    N = a * N + bb * sn;
    D = a * D + bb * sd;
    M = fmaxf(Md, sm);
}

__global__ __launch_bounds__(512, 4)
void wkv_fwd(const float* __restrict__ td_in, const float* __restrict__ kin,
             const float* __restrict__ tf_in, const float* __restrict__ vin,
             const float* __restrict__ m0, const float* __restrict__ n0,
             const float* __restrict__ d0,
             float* __restrict__ out, float* __restrict__ m_out,
             float* __restrict__ n_out, float* __restrict__ dn_out,
             int B, int S, int H)
{
    __shared__ float smry[2][NW][3][32];     // 6 KiB (double-buffered)
    __shared__ float cry[2][3][32];          // 768 B

    const int tid  = threadIdx.x;
    const int lane = tid & 63;
    const int w    = tid >> 6;               // wave id 0..7
    const int c    = lane & 31;              // channel within group
    const int s    = lane >> 5;              // half: 0 = first 8 steps

    const int bpb = H >> 5;                  // 32-ch groups per batch
    const int b   = blockIdx.x / bpb;
    const int hb  = (blockIdx.x - b * bpb) << 5;
    const int h   = hb + c;
    const int g   = b * H + h;

    constexpr float Cc = 1.4426950408889634f;   // log2(e)
    constexpr float IC = 0.6931471805599453f;   // ln(2)

    const float tds    = -ex2(td_in[h] * Cc) * Cc;  // per-step decay (log2)
    const float tfs    = tf_in[h] * Cc;
    const float dseg8  = tds * (float)SUBL;
    const float dseg16 = tds * (float)WSTEPS;

    if (w == 0 && s == 0) {                   // tile-0 carry = init state
        cry[0][0][c] = m0[g] * Cc;
        cry[0][1][c] = n0[g];
        cry[0][2][c] = d0[g];
    }

    const size_t base = (size_t)b * (size_t)S * (size_t)H + (size_t)hb;
    const float* gk = kin + base;
    const float* gv = vin + base;
    float*       go = out + base;

    const int row0   = w * WSTEPS + s * SUBL; // this lane's first row in tile
    const int ntiles = S / TILE;

    float fM = 0.f, fN = 0.f, fD = 0.f;       // (w7,s0) final state

    // Register double-buffers for this lane's 8 (k,v) rows.
    float ka[SUBL], va[SUBL], kb[SUBL], vb[SUBL];

    // Prologue: issue loads for tile 0 into set A.
    #pragma unroll
    for (int j = 0; j < SUBL; ++j) {
        ka[j] = gk[(size_t)(row0 + j) * (size_t)H + c];
        va[j] = gv[(size_t)(row0 + j) * (size_t)H + c];
    }

    auto body = [&](int it, float (&ck)[SUBL], float (&cv)[SUBL],
                    float (&nk)[SUBL], float (&nv)[SUBL])
                __attribute__((always_inline)) -> void {
        // Issue-early prefetch of tile it+1 (no wait precedes this; the
        // compiler's auto-vmcnt before first ck use waits only on the
        // older current-tile loads).
        if (it + 1 < ntiles) {
            const size_t r1 = (size_t)(it + 1) * TILE + row0;
            #pragma unroll
            for (int j = 0; j < SUBL; ++j) {
                nk[j] = gk[(r1 + j) * (size_t)H + c];
                nv[j] = gv[(r1 + j) * (size_t)H + c];
            }
        }

        const int p = it & 1;

        // ---- Phase A: 8-step local scan (neutral init); scale k in place --
        float lm = -1e30f, ln = 0.f, ld = 0.f;
        #pragma unroll
        for (int j = 0; j < SUBL; ++j) {
            const float kt = ck[j] * Cc;
            ck[j] = kt;                        // keep scaled for phase B
            const float vt  = cv[j];
            const float mpd = lm + tds;
            const float d   = mpd - kt;        // max-trick: one factor is 1
            const float e   = ex2(-fabsf(d));
            const bool  cc  = d >= 0.f;
            const float e1  = cc ? 1.f : e;
            const float e2  = cc ? e : 1.f;
            ln = e1 * ln + e2 * vt;
            ld = e1 * ld + e2;
            lm = fmaxf(mpd, kt);
        }

        // ---- Exchange halves: each half gets the other's totals ----------
        const float om = __shfl_xor(lm, 32);
        const float on = __shfl_xor(ln, 32);
        const float od = __shfl_xor(ld, 32);

        // Combined 16-step wave summary (identical in both halves).
        float wm = s ? om : lm, wn = s ? on : ln, wd = s ? od : ld;
        {
            const float sm2 = s ? lm : om;
            const float sn2 = s ? ln : on;
            const float sd2 = s ? ld : od;
            merge(wm, wn, wd, dseg8, sm2, sn2, sd2);
        }
        if (s == 0) {
            smry[p][w][0][c] = wm;
            smry[p][w][1][c] = wn;
            smry[p][w][2][c] = wd;
        }
        BARR;                                 // only barrier per tile
                                              // (lgkmcnt only — vmem
                                              //  prefetch stays in flight)

        // ---- Block compose: incoming state at step w*16 ------------------
        float M = cry[p][0][c];
        float N = cry[p][1][c];
        float D = cry[p][2][c];
        #pragma unroll
        for (int j = 0; j < NW - 1; ++j) {
            const float sm = smry[p][j][0][c];
            const float sn = smry[p][j][1][c];
            const float sd = smry[p][j][2][c];
            if (j < w) merge(M, N, D, dseg16, sm, sn, sd);
        }

        // Wave 7 / half 0: tile carry (incoming + combined wave summary).
        if (w == NW - 1 && s == 0) {
            fM = M; fN = N; fD = D;
            merge(fM, fN, fD, dseg16, wm, wn, wd);
            cry[p ^ 1][0][c] = fM;
            cry[p ^ 1][1][c] = fN;
            cry[p ^ 1][2][c] = fD;
        }

        // Half 1: advance through half 0's 8 steps (om/on/od = its totals).
        if (s == 1) merge(M, N, D, dseg8, om, on, od);

        // ---- Phase B: serial replay with output stores -------------------
        float* po = go + ((size_t)it * TILE + row0) * (size_t)H;
        #pragma unroll
        for (int j = 0; j < SUBL; ++j) {
            const float kt  = ck[j];
            const float vt  = cv[j];
            const float ktf = kt + tfs;
            const float dd  = M - ktf;
            const float eo  = ex2(-fabsf(dd));
            const bool  co  = dd >= 0.f;
            const float e1o = co ? 1.f : eo;
            const float e2o = co ? eo : 1.f;
            po[(size_t)j * H + c] =
                (e1o * N + e2o * vt) * rcpf(fmaf(e1o, D, e2o));
            const float mpd = M + tds;
            const float ds_ = mpd - kt;
            const float es  = ex2(-fabsf(ds_));
            const bool  cs  = ds_ >= 0.f;
            const float e1s = cs ? 1.f : es;
            const float e2s = cs ? es : 1.f;
            N = e1s * N + e2s * vt;
            D = e1s * D + e2s;
            M = fmaxf(mpd, kt);
        }
    };

    int it = 0;
    for (; it + 1 < ntiles; it += 2) {
        body(it,     ka, va, kb, vb);
        body(it + 1, kb, vb, ka, va);
    }
    if (it < ntiles) body(it, ka, va, kb, vb);

    if (w == NW - 1 && s == 0) {              // final states
        m_out[g]  = fM * IC;
        n_out[g]  = fN;
        dn_out[g] = fD;
    }
}

// Safety fallback (serial per channel) for shapes the tiled kernel can't take.
__global__ __launch_bounds__(64)
void wkv_fwd_serial(const float* __restrict__ td_in, const float* __restrict__ kin,
                    const float* __restrict__ tf_in, const float* __restrict__ vin,
                    const float* __restrict__ m0, const float* __restrict__ n0,
                    const float* __restrict__ d0,
                    float* __restrict__ out, float* __restrict__ m_out,
                    float* __restrict__ n_out, float* __restrict__ dn_out,
                    int B, int S, int H)
{
    const int g = blockIdx.x * 64 + threadIdx.x;
    if (g >= B * H) return;
    const int b = g / H;
    const int h = g - b * H;
    constexpr float Cc = 1.4426950408889634f, IC = 0.6931471805599453f;
    const float tds = -ex2(td_in[h] * Cc) * Cc;
    const float tfs = tf_in[h] * Cc;
    float M = m0[g] * Cc, N = n0[g], D = d0[g];
    const size_t base = (size_t)b * S * H + h;
    for (int t = 0; t < S; ++t) {
        const float kt  = kin[base + (size_t)t * H] * Cc;
        const float vt  = vin[base + (size_t)t * H];
        const float ktf = kt + tfs;
        const float mo  = fmaxf(M, ktf);
        const float e1o = ex2(M - mo), e2o = ex2(ktf - mo);
        out[base + (size_t)t * H] = (e1o * N + e2o * vt) * rcpf(e1o * D + e2o);
        const float mpd = M + tds;
        const float ms  = fmaxf(mpd, kt);
        const float e1s = ex2(mpd - ms), e2s = ex2(kt - ms);
        N = e1s * N + e2s * vt;
        D = e1s * D + e2s;
        M = ms;
    }
    m_out[g] = M * IC; n_out[g] = N; dn_out[g] = D;
}

extern "C" void kernel_launch(void* const* d_in, const int* in_sizes, int n_in,
                              void* d_out, int out_size, void* d_ws, size_t ws_size,
                              hipStream_t stream)
{
    const float* time_decay = (const float*)d_in[0];
    const float* key        = (const float*)d_in[1];
    const float* time_first = (const float*)d_in[2];
    const float* value      = (const float*)d_in[3];
    const float* max_state  = (const float*)d_in[4];
    const float* num_state  = (const float*)d_in[5];
    const float* den_state  = (const float*)d_in[6];

    const int H  = in_sizes[0];
    const int BH = in_sizes[4];
    const int B  = BH / H;
    const int S  = in_sizes[1] / BH;

    float* out    = (float*)d_out;
    float* m_out  = out + (size_t)B * (size_t)S * (size_t)H;
    float* n_out  = m_out + BH;
    float* dn_out = n_out + BH;

    if ((H % 32 == 0) && (S % TILE == 0)) {
        const int grid = BH / 32;               // 512 blocks = 2 per CU
        wkv_fwd<<<grid, 512, 0, stream>>>(time_decay, key, time_first, value,
                                          max_state, num_state, den_state,
                                          out, m_out, n_out, dn_out, B, S, H);
    } else {
        const int grid = (BH + 63) / 64;
        wkv_fwd_serial<<<grid, 64, 0, stream>>>(time_decay, key, time_first, value,
                                                max_state, num_state, den_state,
                                                out, m_out, n_out, dn_out, B, S, H);
    }
}